// Round 9
// baseline (205.925 us; speedup 1.0000x reference)
//
#include <hip/hip_runtime.h>
#include <hip/hip_bf16.h>

// ViT embed: patchify + linear + cls + posemb + LayerNorm, fused.
// images [128,3,224,224] f32 -> out [128,197,768] f32.
// M = 128*196 = 25088 patch-rows, K = 768, N = 768.
// v9 = R8 structure + MANUAL load pipeline. Evidence R1-R8: hipcc sinks
// every global load to just-before-use (1 in flight/wave; R8: VGPR=64
// chosen under a 128 budget) -> 10 loads/step serialize at ~800cy. Fix:
// issue step k+1's 10 loads as asm volatile global_load_dwordx4 into NAMED
// ping/pong vars (R6 failed on array/indirect operands, not on vec types),
// then one counted s_waitcnt vmcnt(10) + sched_barrier(0) (rule #18), then
// compute step k. Compiler can't sink asm loads and adds no waits for them.

#define IMG_B 128
#define IMG_C 3
#define IMG_HW 224
#define DTOK 768
#define NTOK 197
#define MROWS 25088

typedef __attribute__((ext_vector_type(4))) float f32x4;
typedef __attribute__((ext_vector_type(8))) short bf16x8;

__device__ __forceinline__ unsigned short f2b(float f) {
  union { float f; unsigned u; } v; v.f = f;
  unsigned u = v.u;
  return (unsigned short)((u + 0x7fffu + ((u >> 16) & 1u)) >> 16);
}

__device__ __forceinline__ f32x4 mfma16(bf16x8 a, bf16x8 b, f32x4 c) {
  return __builtin_amdgcn_mfma_f32_16x16x32_bf16(a, b, c, 0, 0, 0);
}

__device__ __forceinline__ bf16x8 cvt8(float4 lo, float4 hi) {
  union { __hip_bfloat162 h2[4]; bf16x8 v; } u;
  u.h2[0] = __float22bfloat162_rn(make_float2(lo.x, lo.y));
  u.h2[1] = __float22bfloat162_rn(make_float2(lo.z, lo.w));
  u.h2[2] = __float22bfloat162_rn(make_float2(hi.x, hi.y));
  u.h2[3] = __float22bfloat162_rn(make_float2(hi.z, hi.w));
  return u.v;
}

// ---------------- setup kernels ----------------

__global__ void conv_w(const float* __restrict__ W, unsigned short* __restrict__ Wb) {
  int i = blockIdx.x * 256 + threadIdx.x;
  if (i < DTOK * DTOK) Wb[i] = f2b(W[i]);
}

__global__ void make_bpos(const float* __restrict__ bias, const float* __restrict__ cls,
                          float* __restrict__ bpos) {
  int i = blockIdx.x * 256 + threadIdx.x;
  if (i >= NTOK * DTOK) return;
  int t = i / DTOK, d = i - (i / DTOK) * DTOK;
  float expo = (float)(d & ~1) * (1.0f / (float)DTOK);
  float angle = (float)t * exp2f(-expo * 13.287712379549449f);
  float pv = (d & 1) ? cosf(angle) : sinf(angle);
  bpos[i] = pv + ((t == 0) ? cls[d] : bias[d]);
}

__global__ __launch_bounds__(256) void cls_kernel(const float* __restrict__ bpos,
                                                  const float* __restrict__ gamma,
                                                  const float* __restrict__ beta,
                                                  float* __restrict__ out) {
  __shared__ float sred[8];
  const int tid = threadIdx.x;
  float v0 = bpos[tid], v1 = bpos[tid + 256], v2 = bpos[tid + 512];
  float s1 = v0 + v1 + v2;
  float s2 = v0 * v0 + v1 * v1 + v2 * v2;
  #pragma unroll
  for (int off = 32; off >= 1; off >>= 1) {
    s1 += __shfl_xor(s1, off, 64);
    s2 += __shfl_xor(s2, off, 64);
  }
  if ((tid & 63) == 0) { sred[(tid >> 6) * 2] = s1; sred[(tid >> 6) * 2 + 1] = s2; }
  __syncthreads();
  float S1 = sred[0] + sred[2] + sred[4] + sred[6];
  float S2 = sred[1] + sred[3] + sred[5] + sred[7];
  float mean = S1 * (1.0f / 768.0f);
  float rstd = rsqrtf(S2 * (1.0f / 768.0f) - mean * mean + 1e-5f);
  float o0 = (v0 - mean) * rstd * gamma[tid] + beta[tid];
  float o1 = (v1 - mean) * rstd * gamma[tid + 256] + beta[tid + 256];
  float o2 = (v2 - mean) * rstd * gamma[tid + 512] + beta[tid + 512];
  for (int b = 0; b < IMG_B; ++b) {
    float* op = out + (size_t)b * NTOK * DTOK;
    op[tid] = o0; op[tid + 256] = o1; op[tid + 512] = o2;
  }
}

// ---------------- main fused kernel ----------------
// 512 thr / 8 waves. Block = 32 rows x 768 cols; wave = 32 rows x 96 cols
// (2 mf x 6 nf, acc = 48). Barrier-free K-loop, manual asm load pipeline.

#define GLD4(dst, ptr) \
  asm volatile("global_load_dwordx4 %0, %1, off" : "=v"(dst) : "v"(ptr))

__global__ __launch_bounds__(512, 2) void vit_main(
    const float* __restrict__ images, const unsigned short* __restrict__ Wb,
    const float* __restrict__ bpos, const float* __restrict__ gamma,
    const float* __restrict__ beta, float* __restrict__ out) {
  __shared__ float red[8][32][2];
  __shared__ float rowstat[32][2];

  const int tid = threadIdx.x;
  const int wid = tid >> 6;       // n-slice 0..7
  const int lane = tid & 63;
  const int l15 = lane & 15;
  const int g = lane >> 4;
  const int blk = blockIdx.x;
  const int cbase = wid * 96;

  // A row base pointers (mf = 0,1): row m = blk*32 + mf*16 + l15.
  const float* abase0;
  const float* abase1;
  {
    int m = blk * 32 + l15;
    int sb = m / 196, sp = m - (m / 196) * 196;
    int spy = sp / 14, spx = sp - (sp / 14) * 14;
    abase0 = images + (size_t)sb * (IMG_C * IMG_HW * IMG_HW) +
             (spy * 16) * IMG_HW + spx * 16 + (g & 1) * 8;
    m = blk * 32 + 16 + l15;
    sb = m / 196; sp = m - (m / 196) * 196;
    spy = sp / 14; spx = sp - (sp / 14) * 14;
    abase1 = images + (size_t)sb * (IMG_C * IMG_HW * IMG_HW) +
             (spy * 16) * IMG_HW + spx * 16 + (g & 1) * 8;
  }
  const int gb = g >> 1;

  // B per-lane base per nf
  const unsigned short* bb0 = Wb + (size_t)(cbase + 0 * 16 + l15) * DTOK + g * 8;
  const unsigned short* bb1 = Wb + (size_t)(cbase + 1 * 16 + l15) * DTOK + g * 8;
  const unsigned short* bb2 = Wb + (size_t)(cbase + 2 * 16 + l15) * DTOK + g * 8;
  const unsigned short* bb3 = Wb + (size_t)(cbase + 3 * 16 + l15) * DTOK + g * 8;
  const unsigned short* bb4 = Wb + (size_t)(cbase + 4 * 16 + l15) * DTOK + g * 8;
  const unsigned short* bb5 = Wb + (size_t)(cbase + 5 * 16 + l15) * DTOK + g * 8;

  f32x4 acc00 = (f32x4)(0.f), acc01 = (f32x4)(0.f), acc02 = (f32x4)(0.f);
  f32x4 acc03 = (f32x4)(0.f), acc04 = (f32x4)(0.f), acc05 = (f32x4)(0.f);
  f32x4 acc10 = (f32x4)(0.f), acc11 = (f32x4)(0.f), acc12 = (f32x4)(0.f);
  f32x4 acc13 = (f32x4)(0.f), acc14 = (f32x4)(0.f), acc15 = (f32x4)(0.f);

  // ping/pong load destinations (named: asm "v" needs direct, not indirect)
  float4 va0l0, va0h0, va1l0, va1h0, va0l1, va0h1, va1l1, va1h1;
  bf16x8 vb00, vb10, vb20, vb30, vb40, vb50, vb01, vb11, vb21, vb31, vb41, vb51;

#define ISSUE(S, T)                                                         \
  {                                                                         \
    const int i_ = 2 * (T) + gb;                                            \
    const int ao_ = (i_ >> 4) * (IMG_HW * IMG_HW) + (i_ & 15) * IMG_HW;     \
    GLD4(va0l##S, abase0 + ao_);                                            \
    GLD4(va0h##S, abase0 + ao_ + 4);                                        \
    GLD4(va1l##S, abase1 + ao_);                                            \
    GLD4(va1h##S, abase1 + ao_ + 4);                                        \
    GLD4(vb0##S, bb0 + (T) * 32);                                           \
    GLD4(vb1##S, bb1 + (T) * 32);                                           \
    GLD4(vb2##S, bb2 + (T) * 32);                                           \
    GLD4(vb3##S, bb3 + (T) * 32);                                           \
    GLD4(vb4##S, bb4 + (T) * 32);                                           \
    GLD4(vb5##S, bb5 + (T) * 32);                                           \
  }

#define COMPUTE(S)                                                          \
  {                                                                         \
    const bf16x8 af0 = cvt8(va0l##S, va0h##S);                              \
    const bf16x8 af1 = cvt8(va1l##S, va1h##S);                              \
    acc00 = mfma16(af0, vb0##S, acc00); acc10 = mfma16(af1, vb0##S, acc10); \
    acc01 = mfma16(af0, vb1##S, acc01); acc11 = mfma16(af1, vb1##S, acc11); \
    acc02 = mfma16(af0, vb2##S, acc02); acc12 = mfma16(af1, vb2##S, acc12); \
    acc03 = mfma16(af0, vb3##S, acc03); acc13 = mfma16(af1, vb3##S, acc13); \
    acc04 = mfma16(af0, vb4##S, acc04); acc14 = mfma16(af1, vb4##S, acc14); \
    acc05 = mfma16(af0, vb5##S, acc05); acc15 = mfma16(af1, vb5##S, acc15); \
  }

#define STEP(S, NS, T)                                                      \
  ISSUE(NS, (T) + 1);                                                       \
  asm volatile("s_waitcnt vmcnt(10)" ::: "memory");                         \
  __builtin_amdgcn_sched_barrier(0);                                        \
  COMPUTE(S);

  ISSUE(0, 0);
  STEP(0, 1, 0)  STEP(1, 0, 1)  STEP(0, 1, 2)  STEP(1, 0, 3)
  STEP(0, 1, 4)  STEP(1, 0, 5)  STEP(0, 1, 6)  STEP(1, 0, 7)
  STEP(0, 1, 8)  STEP(1, 0, 9)  STEP(0, 1, 10) STEP(1, 0, 11)
  STEP(0, 1, 12) STEP(1, 0, 13) STEP(0, 1, 14) STEP(1, 0, 15)
  STEP(0, 1, 16) STEP(1, 0, 17) STEP(0, 1, 18) STEP(1, 0, 19)
  STEP(0, 1, 20) STEP(1, 0, 21) STEP(0, 1, 22)
  // tail: step 23 (set 1), nothing left to issue
  asm volatile("s_waitcnt vmcnt(0)" ::: "memory");
  __builtin_amdgcn_sched_barrier(0);
  COMPUTE(1);

#undef STEP
#undef COMPUTE
#undef ISSUE

  // gather named accs for the epilogue loops (all-constant indexing -> SROA)
  f32x4 acc[2][6];
  acc[0][0] = acc00; acc[0][1] = acc01; acc[0][2] = acc02;
  acc[0][3] = acc03; acc[0][4] = acc04; acc[0][5] = acc05;
  acc[1][0] = acc10; acc[1][1] = acc11; acc[1][2] = acc12;
  acc[1][3] = acc13; acc[1][4] = acc14; acc[1][5] = acc15;

  // ---- epilogue: +bias+pos, row LN over full 768 ----
  float s1[8], s2[8];
  #pragma unroll
  for (int mf = 0; mf < 2; ++mf) {
    #pragma unroll
    for (int r = 0; r < 4; ++r) {
      const int rl = mf * 16 + g * 4 + r;
      const int m = blk * 32 + rl;
      const int trow = 1 + (m % 196);
      const float* bp = bpos + (size_t)trow * DTOK + cbase + l15;
      float a1 = 0.f, a2 = 0.f;
      #pragma unroll
      for (int nf = 0; nf < 6; ++nf) {
        float val = acc[mf][nf][r] + bp[nf * 16];
        acc[mf][nf][r] = val;
        a1 += val; a2 += val * val;
      }
      s1[mf * 4 + r] = a1; s2[mf * 4 + r] = a2;
    }
  }
  #pragma unroll
  for (int off = 8; off >= 1; off >>= 1) {
    #pragma unroll
    for (int i = 0; i < 8; ++i) {
      s1[i] += __shfl_xor(s1[i], off, 64);
      s2[i] += __shfl_xor(s2[i], off, 64);
    }
  }
  if (l15 == 0) {
    #pragma unroll
    for (int mf = 0; mf < 2; ++mf)
      #pragma unroll
      for (int r = 0; r < 4; ++r) {
        const int rl = mf * 16 + g * 4 + r;
        red[wid][rl][0] = s1[mf * 4 + r];
        red[wid][rl][1] = s2[mf * 4 + r];
      }
  }
  __syncthreads();
  if (tid < 32) {
    float S1 = 0.f, S2 = 0.f;
    #pragma unroll
    for (int w = 0; w < 8; ++w) { S1 += red[w][tid][0]; S2 += red[w][tid][1]; }
    float mean = S1 * (1.0f / 768.0f);
    float var = S2 * (1.0f / 768.0f) - mean * mean;
    rowstat[tid][0] = mean;
    rowstat[tid][1] = rsqrtf(var + 1e-5f);
  }
  __syncthreads();

  float gm[6], bt[6];
  #pragma unroll
  for (int nf = 0; nf < 6; ++nf) {
    gm[nf] = gamma[cbase + nf * 16 + l15];
    bt[nf] = beta[cbase + nf * 16 + l15];
  }
  #pragma unroll
  for (int mf = 0; mf < 2; ++mf) {
    #pragma unroll
    for (int r = 0; r < 4; ++r) {
      const int rl = mf * 16 + g * 4 + r;
      const int m = blk * 32 + rl;
      const int bb = m / 196;
      const int orow = bb * 197 + 1 + (m - bb * 196);
      const float mean = rowstat[rl][0], rstd = rowstat[rl][1];
      float* op = out + (size_t)orow * DTOK + cbase + l15;
      #pragma unroll
      for (int nf = 0; nf < 6; ++nf)
        op[nf * 16] = (acc[mf][nf][r] - mean) * rstd * gm[nf] + bt[nf];
    }
  }
}

extern "C" void kernel_launch(void* const* d_in, const int* in_sizes, int n_in,
                              void* d_out, int out_size, void* d_ws, size_t ws_size,
                              hipStream_t stream) {
  const float* images = (const float*)d_in[0];
  const float* W      = (const float*)d_in[1];
  const float* bias   = (const float*)d_in[2];
  const float* cls    = (const float*)d_in[3];
  const float* gamma  = (const float*)d_in[4];
  const float* beta   = (const float*)d_in[5];
  float* out = (float*)d_out;

  unsigned short* Wb = (unsigned short*)d_ws;                       // 768*768*2 B
  float* bpos = (float*)((char*)d_ws + (size_t)DTOK * DTOK * 2);    // 197*768*4 B

  conv_w<<<(DTOK * DTOK + 255) / 256, 256, 0, stream>>>(W, Wb);
  make_bpos<<<(NTOK * DTOK + 255) / 256, 256, 0, stream>>>(bias, cls, bpos);
  cls_kernel<<<1, 256, 0, stream>>>(bpos, gamma, beta, out);
  vit_main<<<MROWS / 32, 512, 0, stream>>>(images, Wb, bpos, gamma, beta, out);
}

// Round 10
// 130.121 us; speedup vs baseline: 1.5826x; 1.5826x over previous
//
#include <hip/hip_runtime.h>
#include <hip/hip_bf16.h>

// ViT embed: patchify + linear + cls + posemb + LayerNorm, fused.
// images [128,3,224,224] f32 -> out [128,197,768] f32.
// v10: continuous-DMA K-loop. B staged via global_load_lds into a TRIPLE
// buffered LDS tile (48KB x3, dynamic LDS) with counted s_waitcnt vmcnt(14)
// + one raw s_barrier per step -> the DMA stream never drains (2-step
// slack). A-fragments direct from global (R3-proven), no A-LDS, no
// ds_writes. 64 rows x 768 cols, 8 waves, BK=32, 24 steps, LN fused.

#define IMG_B 128
#define IMG_C 3
#define IMG_HW 224
#define DTOK 768
#define NTOK 197
#define MROWS 25088

typedef __attribute__((ext_vector_type(4))) float f32x4;
typedef __attribute__((ext_vector_type(8))) short bf16x8;

__device__ __forceinline__ unsigned short f2b(float f) {
  union { float f; unsigned u; } v; v.f = f;
  unsigned u = v.u;
  return (unsigned short)((u + 0x7fffu + ((u >> 16) & 1u)) >> 16);
}

__device__ __forceinline__ bf16x8 cvt8(float4 lo, float4 hi) {
  union { __hip_bfloat162 h2[4]; bf16x8 v; } u;
  u.h2[0] = __float22bfloat162_rn(make_float2(lo.x, lo.y));
  u.h2[1] = __float22bfloat162_rn(make_float2(lo.z, lo.w));
  u.h2[2] = __float22bfloat162_rn(make_float2(hi.x, hi.y));
  u.h2[3] = __float22bfloat162_rn(make_float2(hi.z, hi.w));
  return u.v;
}

__device__ __forceinline__ void glds16(const void* g, void* l) {
  __builtin_amdgcn_global_load_lds(
      (const __attribute__((address_space(1))) unsigned int*)g,
      (__attribute__((address_space(3))) unsigned int*)l, 16, 0, 0);
}

// ---------------- setup kernels ----------------

__global__ void conv_w(const float* __restrict__ W, unsigned short* __restrict__ Wb) {
  int i = blockIdx.x * 256 + threadIdx.x;
  if (i < DTOK * DTOK) Wb[i] = f2b(W[i]);
}

__global__ void make_bpos(const float* __restrict__ bias, const float* __restrict__ cls,
                          float* __restrict__ bpos) {
  int i = blockIdx.x * 256 + threadIdx.x;
  if (i >= NTOK * DTOK) return;
  int t = i / DTOK, d = i - (i / DTOK) * DTOK;
  float expo = (float)(d & ~1) * (1.0f / (float)DTOK);
  float angle = (float)t * exp2f(-expo * 13.287712379549449f);
  float pv = (d & 1) ? cosf(angle) : sinf(angle);
  bpos[i] = pv + ((t == 0) ? cls[d] : bias[d]);
}

__global__ __launch_bounds__(256) void cls_kernel(const float* __restrict__ bpos,
                                                  const float* __restrict__ gamma,
                                                  const float* __restrict__ beta,
                                                  float* __restrict__ out) {
  __shared__ float sred[8];
  const int tid = threadIdx.x;
  float v0 = bpos[tid], v1 = bpos[tid + 256], v2 = bpos[tid + 512];
  float s1 = v0 + v1 + v2;
  float s2 = v0 * v0 + v1 * v1 + v2 * v2;
  #pragma unroll
  for (int off = 32; off >= 1; off >>= 1) {
    s1 += __shfl_xor(s1, off, 64);
    s2 += __shfl_xor(s2, off, 64);
  }
  if ((tid & 63) == 0) { sred[(tid >> 6) * 2] = s1; sred[(tid >> 6) * 2 + 1] = s2; }
  __syncthreads();
  float S1 = sred[0] + sred[2] + sred[4] + sred[6];
  float S2 = sred[1] + sred[3] + sred[5] + sred[7];
  float mean = S1 * (1.0f / 768.0f);
  float rstd = rsqrtf(S2 * (1.0f / 768.0f) - mean * mean + 1e-5f);
  float o0 = (v0 - mean) * rstd * gamma[tid] + beta[tid];
  float o1 = (v1 - mean) * rstd * gamma[tid + 256] + beta[tid + 256];
  float o2 = (v2 - mean) * rstd * gamma[tid + 512] + beta[tid + 512];
  for (int b = 0; b < IMG_B; ++b) {
    float* op = out + (size_t)b * NTOK * DTOK;
    op[tid] = o0; op[tid + 256] = o1; op[tid + 512] = o2;
  }
}

// ---------------- main fused kernel ----------------
// 512 thr / 8 waves (n-slices of 96). BM=64, BK=32, 24 K-steps.
// B LDS tile (per buf): row r (0..767) of 32 bf16 = 4 16B slots; content
// quad q stored at slot q ^ ((r>>1)&3) -> conflict-free b128 reads
// (verified 0 conflicts + correct numerics in R4/R5).

__global__ __launch_bounds__(512, 2) void vit_main(
    const float* __restrict__ images, const unsigned short* __restrict__ Wb,
    const float* __restrict__ bpos, const float* __restrict__ gamma,
    const float* __restrict__ beta, float* __restrict__ out) {
  extern __shared__ unsigned short Bl[];   // 3 x 24576 ushorts = 144KB
  __shared__ float red[8][64][2];
  __shared__ float rowstat[64][2];

  const int tid = threadIdx.x;
  const int wid = tid >> 6;
  const int lane = tid & 63;
  const int l15 = lane & 15;
  const int g = lane >> 4;
  const int blkraw = blockIdx.x;
  const int blk = (blkraw & 7) * 49 + (blkraw >> 3);   // XCD swizzle (392 = 8*49)
  const int cbase = wid * 96;
  const int gb = g >> 1;

  // ---- A: direct-global fragment bases (R3-proven). Row m = blk*64+mf*16+l15;
  // lane k-span g*8..g*8+7 -> fold (g&1)*8; per-step idx = 2*it + gb:
  // offset = (idx>>4)*50176 + (idx&15)*224.
  const float* abase[4];
  #pragma unroll
  for (int mf = 0; mf < 4; ++mf) {
    const int m = blk * 64 + mf * 16 + l15;
    const int sb = m / 196;
    const int sp = m - sb * 196;
    const int spy = sp / 14, spx = sp - (sp / 14) * 14;
    abase[mf] = images + (size_t)sb * (IMG_C * IMG_HW * IMG_HW) +
                (spy * 16) * IMG_HW + spx * 16 + (g & 1) * 8;
  }

  // ---- B glds staging (R4-proven): linear dest slot d = j*512+tid;
  // source row r = d>>2, quad q = (d&3) ^ ((r>>1)&3); step k adds k*32.
  int boff[6];
  #pragma unroll
  for (int j = 0; j < 6; ++j) {
    const int d = j * 512 + tid;
    const int r = d >> 2;
    const int q = (d & 3) ^ ((r >> 1) & 3);
    boff[j] = r * DTOK + q * 8;
  }
  const int bldsbase = wid * 512;            // per-wave ushort base within a buf
  const int sA = g ^ ((l15 >> 1) & 3);       // frag-read swizzle
  const int brd = cbase * 32 + l15 * 32 + sA * 8;

  f32x4 acc[4][6];
  #pragma unroll
  for (int mf = 0; mf < 4; ++mf)
    #pragma unroll
    for (int nf = 0; nf < 6; ++nf)
      acc[mf][nf] = (f32x4)(0.0f);

  float4 aimg[2][8];   // A(k) lives in aimg[k&1]; all indices literal

#define AOFF(T) ((((2 * (T) + 0) >> 4)) * 50176)  /* helper unused; kept simple below */

  // ---- prologue: A(0); fence; G(0)->buf0; G(1)->buf1 ----
  {
    const int idx0 = gb;                       // it = 0
    const int ao = (idx0 >> 4) * 50176 + (idx0 & 15) * 224;
    #pragma unroll
    for (int mf = 0; mf < 4; ++mf) {
      aimg[0][mf * 2]     = *(const float4*)(abase[mf] + ao);
      aimg[0][mf * 2 + 1] = *(const float4*)(abase[mf] + ao + 4);
    }
    asm volatile("" ::: "memory");
    #pragma unroll
    for (int j = 0; j < 6; ++j)
      glds16(Wb + boff[j], Bl + 0 * 24576 + bldsbase + j * 4096);
    #pragma unroll
    for (int j = 0; j < 6; ++j)
      glds16(Wb + boff[j] + 32, Bl + 1 * 24576 + bldsbase + j * 4096);
    asm volatile("" ::: "memory");
  }

  // ---- steady step: vmcnt(CNT); barrier; issue A(K+1), G(K+2); fence; compute K.
  // CNT retires G(K) exactly: steady = A(K):8 + G(K+1):6 = 14.
#define STEP(K, CNT)                                                           \
  {                                                                            \
    asm volatile("s_waitcnt vmcnt(" CNT ")" ::: "memory");                     \
    __builtin_amdgcn_s_barrier();                                              \
    if ((K) + 1 < 24) {                                                        \
      const int idxn_ = 2 * ((K) + 1) + gb;                                    \
      const int aon_ = (idxn_ >> 4) * 50176 + (idxn_ & 15) * 224;              \
      _Pragma("unroll")                                                        \
      for (int mf = 0; mf < 4; ++mf) {                                         \
        aimg[((K) + 1) & 1][mf * 2]     = *(const float4*)(abase[mf] + aon_);  \
        aimg[((K) + 1) & 1][mf * 2 + 1] = *(const float4*)(abase[mf] + aon_ + 4); \
      }                                                                        \
    }                                                                          \
    if ((K) + 2 < 24) {                                                        \
      _Pragma("unroll")                                                        \
      for (int j = 0; j < 6; ++j)                                              \
        glds16(Wb + boff[j] + ((K) + 2) * 32,                                  \
               Bl + (((K) + 2) % 3) * 24576 + bldsbase + j * 4096);            \
    }                                                                          \
    asm volatile("" ::: "memory");                                             \
    bf16x8 afr[4];                                                             \
    _Pragma("unroll")                                                          \
    for (int mf = 0; mf < 4; ++mf)                                             \
      afr[mf] = cvt8(aimg[(K) & 1][mf * 2], aimg[(K) & 1][mf * 2 + 1]);        \
    _Pragma("unroll")                                                          \
    for (int nf = 0; nf < 6; ++nf) {                                           \
      const bf16x8 bf =                                                        \
          *(const bf16x8*)(Bl + ((K) % 3) * 24576 + brd + nf * 512);           \
      _Pragma("unroll")                                                        \
      for (int mf = 0; mf < 4; ++mf)                                           \
        acc[mf][nf] = __builtin_amdgcn_mfma_f32_16x16x32_bf16(                 \
            afr[mf], bf, acc[mf][nf], 0, 0, 0);                                \
    }                                                                          \
  }

  STEP(0, "0")
  STEP(1, "14")  STEP(2, "14")  STEP(3, "14")  STEP(4, "14")
  STEP(5, "14")  STEP(6, "14")  STEP(7, "14")  STEP(8, "14")
  STEP(9, "14")  STEP(10, "14") STEP(11, "14") STEP(12, "14")
  STEP(13, "14") STEP(14, "14") STEP(15, "14") STEP(16, "14")
  STEP(17, "14") STEP(18, "14") STEP(19, "14") STEP(20, "14")
  STEP(21, "14") STEP(22, "14") STEP(23, "8")
#undef STEP

  // ---- epilogue: +bias+pos, row LN over full 768 (all in-block) ----
  float s1[16], s2[16];
  #pragma unroll
  for (int mf = 0; mf < 4; ++mf) {
    #pragma unroll
    for (int r = 0; r < 4; ++r) {
      const int rl = mf * 16 + g * 4 + r;
      const int m = blk * 64 + rl;
      const int trow = 1 + (m % 196);
      const float* bp = bpos + (size_t)trow * DTOK + cbase + l15;
      float a1 = 0.f, a2 = 0.f;
      #pragma unroll
      for (int nf = 0; nf < 6; ++nf) {
        float val = acc[mf][nf][r] + bp[nf * 16];
        acc[mf][nf][r] = val;
        a1 += val; a2 += val * val;
      }
      s1[mf * 4 + r] = a1; s2[mf * 4 + r] = a2;
    }
  }
  #pragma unroll
  for (int off = 8; off >= 1; off >>= 1) {
    #pragma unroll
    for (int i = 0; i < 16; ++i) {
      s1[i] += __shfl_xor(s1[i], off, 64);
      s2[i] += __shfl_xor(s2[i], off, 64);
    }
  }
  __syncthreads();   // all K-loop LDS reads done before red[] reuse-by-name
  if (l15 == 0) {
    #pragma unroll
    for (int mf = 0; mf < 4; ++mf)
      #pragma unroll
      for (int r = 0; r < 4; ++r) {
        const int rl = mf * 16 + g * 4 + r;
        red[wid][rl][0] = s1[mf * 4 + r];
        red[wid][rl][1] = s2[mf * 4 + r];
      }
  }
  __syncthreads();
  if (tid < 64) {
    float S1 = 0.f, S2 = 0.f;
    #pragma unroll
    for (int w = 0; w < 8; ++w) { S1 += red[w][tid][0]; S2 += red[w][tid][1]; }
    float mean = S1 * (1.0f / 768.0f);
    float var = S2 * (1.0f / 768.0f) - mean * mean;
    rowstat[tid][0] = mean;
    rowstat[tid][1] = rsqrtf(var + 1e-5f);
  }
  __syncthreads();

  float gm[6], bt[6];
  #pragma unroll
  for (int nf = 0; nf < 6; ++nf) {
    gm[nf] = gamma[cbase + nf * 16 + l15];
    bt[nf] = beta[cbase + nf * 16 + l15];
  }
  #pragma unroll
  for (int mf = 0; mf < 4; ++mf) {
    #pragma unroll
    for (int r = 0; r < 4; ++r) {
      const int rl = mf * 16 + g * 4 + r;
      const int m = blk * 64 + rl;
      const int bb = m / 196;
      const int orow = bb * 197 + 1 + (m - bb * 196);
      const float mean = rowstat[rl][0], rstd = rowstat[rl][1];
      float* op = out + (size_t)orow * DTOK + cbase + l15;
      #pragma unroll
      for (int nf = 0; nf < 6; ++nf)
        op[nf * 16] = (acc[mf][nf][r] - mean) * rstd * gm[nf] + bt[nf];
    }
  }
}

extern "C" void kernel_launch(void* const* d_in, const int* in_sizes, int n_in,
                              void* d_out, int out_size, void* d_ws, size_t ws_size,
                              hipStream_t stream) {
  const float* images = (const float*)d_in[0];
  const float* W      = (const float*)d_in[1];
  const float* bias   = (const float*)d_in[2];
  const float* cls    = (const float*)d_in[3];
  const float* gamma  = (const float*)d_in[4];
  const float* beta   = (const float*)d_in[5];
  float* out = (float*)d_out;

  unsigned short* Wb = (unsigned short*)d_ws;                       // 768*768*2 B
  float* bpos = (float*)((char*)d_ws + (size_t)DTOK * DTOK * 2);    // 197*768*4 B

  conv_w<<<(DTOK * DTOK + 255) / 256, 256, 0, stream>>>(W, Wb);
  make_bpos<<<(NTOK * DTOK + 255) / 256, 256, 0, stream>>>(bias, cls, bpos);
  cls_kernel<<<1, 256, 0, stream>>>(bpos, gamma, beta, out);
  // dynamic LDS: 3 x 24576 ushorts = 147456 B (+4.6KB static)
  vit_main<<<MROWS / 64, 512, 147456, stream>>>(images, Wb, bpos, gamma, beta, out);
}